// Round 3
// baseline (277.180 us; speedup 1.0000x reference)
//
#include <hip/hip_runtime.h>

typedef unsigned short u16;
typedef __attribute__((ext_vector_type(8))) u16 u16x8;
typedef __attribute__((ext_vector_type(8))) __bf16 bf16x8;
typedef __attribute__((ext_vector_type(4))) float f32x4;

#define LOG2E_F 1.4426950408889634f

__device__ __forceinline__ u16 f2bf(float f) {
  // exact for the small integers we quantize to (|v| <= 8)
  return (u16)(__float_as_uint(f) >> 16);
}
__device__ __forceinline__ float clip87(float x) {
  return fminf(fmaxf(x, -8.0f), 7.0f);
}

// ---------------- scalar means + derived constants ----------------
// scal: [0]=a_in [1]=aq [2]=ak [3]=av [4]=am [5]=ap [6]=escale [7]=am*av
__global__ void k_scalars(const float* __restrict__ qkv_act_alpha,
                          const float* __restrict__ proj_act_alpha,
                          const float* __restrict__ q_alpha,
                          const float* __restrict__ k_alpha,
                          const float* __restrict__ v_alpha,
                          const float* __restrict__ attn_alpha,
                          float* __restrict__ scal) {
  int tid = threadIdx.x;
  int wave = tid >> 6, lane = tid & 63;
  if (wave < 6) {
    const float* src = nullptr; int n = 0;
    switch (wave) {
      case 0: src = qkv_act_alpha;  n = 768; break;
      case 1: src = q_alpha;        n = 12;  break;
      case 2: src = k_alpha;        n = 12;  break;
      case 3: src = v_alpha;        n = 12;  break;
      case 4: src = attn_alpha;     n = 12;  break;
      case 5: src = proj_act_alpha; n = 768; break;
    }
    double s = 0.0;
    for (int i = lane; i < n; i += 64) s += (double)src[i];
    s += __shfl_xor(s, 1);
    s += __shfl_xor(s, 2);
    s += __shfl_xor(s, 4);
    s += __shfl_xor(s, 8);
    s += __shfl_xor(s, 16);
    s += __shfl_xor(s, 32);
    if (lane == 0) scal[wave] = (float)(s / (double)n);
  }
  __syncthreads();
  if (tid == 0) {
    float aq = scal[1], ak = scal[2];
    float s_ = (0.125f * aq) * ak;   // head_scale * aq * ak
    scal[6] = LOG2E_F * s_;          // escale
    scal[7] = scal[4] * scal[3];     // am * av
  }
}

// ---------------- weight quantization ----------------
__global__ __launch_bounds__(256) void k_quant_weights(
    const float* __restrict__ qkv_w, const float* __restrict__ qkv_alpha,
    const float* __restrict__ qkv_b, const float* __restrict__ proj_w,
    const float* __restrict__ proj_alpha, const float* __restrict__ scal,
    u16* __restrict__ wq, u16* __restrict__ wp, float* __restrict__ biasi) {
  int idx = blockIdx.x * 256 + threadIdx.x;
  const int T1 = 2304 * 768, T2 = 768 * 768;
  if (idx < T1) {
    int o = idx / 768;
    wq[idx] = f2bf(rintf(clip87(qkv_w[idx] / qkv_alpha[o])));
  } else if (idx < T1 + T2) {
    int j = idx - T1;
    int o = j / 768;
    wp[j] = f2bf(rintf(clip87(proj_w[j] / proj_alpha[o])));
  } else if (idx < T1 + T2 + 2304) {
    int o = idx - T1 - T2;
    biasi[o] = truncf((qkv_b[o] / scal[0]) / qkv_alpha[o]);
  }
}

// ---------------- x0 activation quantization ----------------
__global__ __launch_bounds__(256) void k_quant_x0(const float* __restrict__ x0,
                                                  const float* __restrict__ scal,
                                                  u16* __restrict__ x0q) {
  int base = (blockIdx.x * 256 + threadIdx.x) * 8;
  float a = scal[0];
  f32x4 v0 = *(const f32x4*)&x0[base];
  f32x4 v1 = *(const f32x4*)&x0[base + 4];
  u16x8 o;
  #pragma unroll
  for (int j = 0; j < 4; j++) o[j] = f2bf(rintf(clip87(v0[j] / a)));
  #pragma unroll
  for (int j = 0; j < 4; j++) o[4 + j] = f2bf(rintf(clip87(v1[j] / a)));
  *(u16x8*)&x0q[base] = o;
}

// ---------------- generic C = A * B^T GEMM (bf16 MFMA, exact int) ----------------
// A: [M][K] bf16 row-major, Bt: [N][K] bf16 row-major. 128x128 tile, BK=32, 4 waves.
// mode 0: Cout[row*N+col] = acc + bias[col]                (qkv)
// mode 1: Cout[row*N+col] = acc*palpha[col]*ap + pbias[col] (proj)
#define LDP 40
__global__ __launch_bounds__(256) void k_gemm_bt(
    const u16* __restrict__ A, const u16* __restrict__ Bt,
    int M, int N, int K, float* __restrict__ Cout,
    const float* __restrict__ bias, const float* __restrict__ palpha,
    const float* __restrict__ pbias, const float* __restrict__ scal, int mode) {
  __shared__ __align__(16) u16 lA[128 * LDP];
  __shared__ __align__(16) u16 lB[128 * LDP];
  int tid = threadIdx.x;
  int lane = tid & 63, wave = tid >> 6;
  int wr = wave >> 1, wc = wave & 1;
  int m0 = blockIdx.y * 128, n0 = blockIdx.x * 128;

  f32x4 acc[4][4];
  #pragma unroll
  for (int mi = 0; mi < 4; mi++)
    #pragma unroll
    for (int ni = 0; ni < 4; ni++) acc[mi][ni] = (f32x4){0.f, 0.f, 0.f, 0.f};

  int r = tid >> 1, ch = (tid & 1) * 16;
  const u16* Ap = A + (size_t)(m0 + r) * K + ch;
  const u16* Bp = Bt + (size_t)(n0 + r) * K + ch;
  u16* lAw = &lA[r * LDP + ch];
  u16* lBw = &lB[r * LDP + ch];

  int arow = wr * 64 + (lane & 15);
  int brow = wc * 64 + (lane & 15);
  int acol = (lane >> 4) * 8;

  for (int k0 = 0; k0 < K; k0 += 32) {
    *(u16x8*)(lAw)     = *(const u16x8*)(Ap + k0);
    *(u16x8*)(lAw + 8) = *(const u16x8*)(Ap + k0 + 8);
    *(u16x8*)(lBw)     = *(const u16x8*)(Bp + k0);
    *(u16x8*)(lBw + 8) = *(const u16x8*)(Bp + k0 + 8);
    __syncthreads();
    bf16x8 af[4], bf[4];
    #pragma unroll
    for (int mi = 0; mi < 4; mi++) af[mi] = *(const bf16x8*)&lA[(arow + mi * 16) * LDP + acol];
    #pragma unroll
    for (int ni = 0; ni < 4; ni++) bf[ni] = *(const bf16x8*)&lB[(brow + ni * 16) * LDP + acol];
    #pragma unroll
    for (int mi = 0; mi < 4; mi++)
      #pragma unroll
      for (int ni = 0; ni < 4; ni++)
        acc[mi][ni] = __builtin_amdgcn_mfma_f32_16x16x32_bf16(af[mi], bf[ni], acc[mi][ni], 0, 0, 0);
    __syncthreads();
  }

  int lrow = (lane >> 4) * 4, lcol = lane & 15;
  if (mode == 0) {
    #pragma unroll
    for (int mi = 0; mi < 4; mi++)
      #pragma unroll
      for (int ni = 0; ni < 4; ni++) {
        int col = n0 + wc * 64 + ni * 16 + lcol;
        float b = bias[col];
        #pragma unroll
        for (int rr = 0; rr < 4; rr++) {
          int row = m0 + wr * 64 + mi * 16 + lrow + rr;
          Cout[(size_t)row * N + col] = acc[mi][ni][rr] + b;
        }
      }
  } else {
    float ap = scal[5];
    #pragma unroll
    for (int mi = 0; mi < 4; mi++)
      #pragma unroll
      for (int ni = 0; ni < 4; ni++) {
        int col = n0 + wc * 64 + ni * 16 + lcol;
        float pa = palpha[col], pb = pbias[col];
        #pragma unroll
        for (int rr = 0; rr < 4; rr++) {
          int row = m0 + wr * 64 + mi * 16 + lrow + rr;
          Cout[(size_t)row * N + col] = (acc[mi][ni][rr] * pa) * ap + pb;
        }
      }
  }
}

// ---------------- q/k/v branch quantization ----------------
// grid: (4, 48) blocks of 256: n = bx*256+tid, bh = by. One thread per (b,h,n) row.
__global__ __launch_bounds__(256) void k_quant_branches(
    const float* __restrict__ qkv, const float* __restrict__ qkv_alpha,
    const float* __restrict__ nqw, const float* __restrict__ nqb,
    const float* __restrict__ nkw, const float* __restrict__ nkb,
    const float* __restrict__ scal, u16* __restrict__ q2, u16* __restrict__ k2,
    u16* __restrict__ v2t) {
  int n = blockIdx.x * 256 + threadIdx.x;
  int bh = blockIdx.y;
  int b = bh / 12, h = bh % 12;
  const float a_in = scal[0], aq = scal[1], ak = scal[2], av = scal[3];
  const float* row = qkv + (size_t)(b * 1024 + n) * 2304;

  float xq[64];
  // ---- q branch ----
  {
    #pragma unroll
    for (int d = 0; d < 64; d++) xq[d] = row[h * 64 + d] * qkv_alpha[h * 64 + d];
    int m = 0, v = 0;
    #pragma unroll
    for (int i = 0; i < 64; i++) {
      int xi = (int)xq[i];
      int dd = xi - m;
      m += (dd * (1024 / (i + 1))) >> 10;   // floor div by 1024
      v += dd * (xi - m);
    }
    float muf = (float)m;
    float den = sqrtf((float)v * 0.015625f) + 1e-5f;
    u16x8* dst = (u16x8*)(q2 + ((size_t)bh * 1024 + n) * 64);
    #pragma unroll
    for (int g = 0; g < 8; g++) {
      u16x8 t8;
      #pragma unroll
      for (int j = 0; j < 8; j++) {
        int d = g * 8 + j;
        float q1 = (xq[d] - muf) / den;
        float bw = nqb[d] / nqw[d];
        float t = (q1 + bw) * nqw[d] / aq;
        t8[j] = f2bf(rintf(clip87(t)));
      }
      dst[g] = t8;
    }
  }
  // ---- k branch ----
  {
    #pragma unroll
    for (int d = 0; d < 64; d++) xq[d] = row[768 + h * 64 + d] * qkv_alpha[768 + h * 64 + d];
    int m = 0, v = 0;
    #pragma unroll
    for (int i = 0; i < 64; i++) {
      int xi = (int)xq[i];
      int dd = xi - m;
      m += (dd * (1024 / (i + 1))) >> 10;
      v += dd * (xi - m);
    }
    float muf = (float)m;
    float den = sqrtf((float)v * 0.015625f) + 1e-5f;
    u16x8* dst = (u16x8*)(k2 + ((size_t)bh * 1024 + n) * 64);
    #pragma unroll
    for (int g = 0; g < 8; g++) {
      u16x8 t8;
      #pragma unroll
      for (int j = 0; j < 8; j++) {
        int d = g * 8 + j;
        float q1 = (xq[d] - muf) / den;
        float bw = nkb[d] / nkw[d];
        float t = (q1 + bw) * nkw[d] / ak;
        t8[j] = f2bf(rintf(clip87(t)));
      }
      dst[g] = t8;
    }
  }
  // ---- v branch (stored transposed: v2t[bh][d][n]) ----
  {
    #pragma unroll
    for (int d = 0; d < 64; d++) {
      float coefv = a_in * qkv_alpha[1536 + h * 64 + d];
      float t = (row[1536 + h * 64 + d] * coefv) / av;
      v2t[((size_t)bh * 64 + d) * 1024 + n] = f2bf(rintf(clip87(t)));
    }
  }
}

// ---------------- fused attention ----------------
// grid (16, 48): qt = bx (64 q rows), bh = by. 4 waves; wave w owns q rows w*16..w*16+15.
__global__ __launch_bounds__(256) void k_attn(
    const u16* __restrict__ q2, const u16* __restrict__ k2,
    const u16* __restrict__ v2t, const float* __restrict__ scal,
    u16* __restrict__ x1q) {
  __shared__ __align__(16) u16 lK[64 * 72];
  __shared__ __align__(16) u16 lV[64 * 72];
  __shared__ __align__(16) u16 lP[64 * 72];
  __shared__ float rs_lds[64];
  int tid = threadIdx.x, lane = tid & 63, wave = tid >> 6;
  int qt = blockIdx.x, bh = blockIdx.y;
  const float escale = scal[6], am = scal[4], am_av = scal[7], apc = scal[5];

  // q fragments (persist): rows = bh*1024 + qt*64 + wave*16 + (lane&15)
  size_t qrow = (size_t)bh * 1024 + qt * 64 + wave * 16 + (lane & 15);
  bf16x8 qf0 = *(const bf16x8*)(q2 + qrow * 64 + (lane >> 4) * 8);
  bf16x8 qf1 = *(const bf16x8*)(q2 + qrow * 64 + 32 + (lane >> 4) * 8);

  const u16* k2b = k2 + (size_t)bh * 1024 * 64;
  const u16* v2b = v2t + (size_t)bh * 64 * 1024;
  int sr = tid >> 2, sc = (tid & 3) * 16;

  // ---- pass 1: row sums of attn_exp ----
  double rsum[4] = {0.0, 0.0, 0.0, 0.0};
  for (int kt = 0; kt < 16; kt++) {
    const u16* src = k2b + (size_t)(kt * 64 + sr) * 64 + sc;
    *(u16x8*)&lK[sr * 72 + sc]     = *(const u16x8*)src;
    *(u16x8*)&lK[sr * 72 + sc + 8] = *(const u16x8*)(src + 8);
    __syncthreads();
    #pragma unroll
    for (int ct = 0; ct < 4; ct++) {
      bf16x8 kf0 = *(const bf16x8*)&lK[(ct * 16 + (lane & 15)) * 72 + (lane >> 4) * 8];
      bf16x8 kf1 = *(const bf16x8*)&lK[(ct * 16 + (lane & 15)) * 72 + 32 + (lane >> 4) * 8];
      f32x4 s = {0.f, 0.f, 0.f, 0.f};
      s = __builtin_amdgcn_mfma_f32_16x16x32_bf16(qf0, kf0, s, 0, 0, 0);
      s = __builtin_amdgcn_mfma_f32_16x16x32_bf16(qf1, kf1, s, 0, 0, 0);
      #pragma unroll
      for (int rr = 0; rr < 4; rr++) {
        float e = escale * s[rr];
        float f = floorf(e);
        float p2 = __uint_as_float((unsigned)((int)f + 127) << 23);
        float pe = p2 * (1.0f + (e - f));
        rsum[rr] += (double)pe;
      }
    }
    __syncthreads();
  }
  #pragma unroll
  for (int rr = 0; rr < 4; rr++) {
    double s = rsum[rr];
    s += __shfl_xor(s, 1);
    s += __shfl_xor(s, 2);
    s += __shfl_xor(s, 4);
    s += __shfl_xor(s, 8);
    if ((lane & 15) == 0) rs_lds[wave * 16 + (lane >> 4) * 4 + rr] = (float)s;
  }
  __syncthreads();
  float rs[4];
  #pragma unroll
  for (int rr = 0; rr < 4; rr++) rs[rr] = rs_lds[wave * 16 + (lane >> 4) * 4 + rr];

  // ---- pass 2: recompute S (bitwise identical), quantize attn, PV GEMM ----
  f32x4 accv[4];
  #pragma unroll
  for (int ct = 0; ct < 4; ct++) accv[ct] = (f32x4){0.f, 0.f, 0.f, 0.f};

  for (int kt = 0; kt < 16; kt++) {
    const u16* srcK = k2b + (size_t)(kt * 64 + sr) * 64 + sc;
    *(u16x8*)&lK[sr * 72 + sc]     = *(const u16x8*)srcK;
    *(u16x8*)&lK[sr * 72 + sc + 8] = *(const u16x8*)(srcK + 8);
    const u16* srcV = v2b + (size_t)sr * 1024 + kt * 64 + sc;
    *(u16x8*)&lV[sr * 72 + sc]     = *(const u16x8*)srcV;
    *(u16x8*)&lV[sr * 72 + sc + 8] = *(const u16x8*)(srcV + 8);
    __syncthreads();
    #pragma unroll
    for (int ct = 0; ct < 4; ct++) {
      bf16x8 kf0 = *(const bf16x8*)&lK[(ct * 16 + (lane & 15)) * 72 + (lane >> 4) * 8];
      bf16x8 kf1 = *(const bf16x8*)&lK[(ct * 16 + (lane & 15)) * 72 + 32 + (lane >> 4) * 8];
      f32x4 s = {0.f, 0.f, 0.f, 0.f};
      s = __builtin_amdgcn_mfma_f32_16x16x32_bf16(qf0, kf0, s, 0, 0, 0);
      s = __builtin_amdgcn_mfma_f32_16x16x32_bf16(qf1, kf1, s, 0, 0, 0);
      #pragma unroll
      for (int rr = 0; rr < 4; rr++) {
        float e = escale * s[rr];
        float f = floorf(e);
        float p2 = __uint_as_float((unsigned)((int)f + 127) << 23);
        float pe = p2 * (1.0f + (e - f));
        float an = pe / rs[rr];
        float a2 = rintf(clip87(an / am));
        lP[(wave * 16 + (lane >> 4) * 4 + rr) * 72 + ct * 16 + (lane & 15)] = f2bf(a2);
      }
    }
    __syncthreads();
    bf16x8 pf0 = *(const bf16x8*)&lP[(wave * 16 + (lane & 15)) * 72 + (lane >> 4) * 8];
    bf16x8 pf1 = *(const bf16x8*)&lP[(wave * 16 + (lane & 15)) * 72 + 32 + (lane >> 4) * 8];
    #pragma unroll
    for (int ct = 0; ct < 4; ct++) {
      bf16x8 vf0 = *(const bf16x8*)&lV[(ct * 16 + (lane & 15)) * 72 + (lane >> 4) * 8];
      bf16x8 vf1 = *(const bf16x8*)&lV[(ct * 16 + (lane & 15)) * 72 + 32 + (lane >> 4) * 8];
      accv[ct] = __builtin_amdgcn_mfma_f32_16x16x32_bf16(pf0, vf0, accv[ct], 0, 0, 0);
      accv[ct] = __builtin_amdgcn_mfma_f32_16x16x32_bf16(pf1, vf1, accv[ct], 0, 0, 0);
    }
    __syncthreads();
  }

  // epilogue: x1_2b quantization, write (B,N,C) layout
  int b = bh / 12, h = bh % 12;
  #pragma unroll
  for (int ct = 0; ct < 4; ct++)
    #pragma unroll
    for (int rr = 0; rr < 4; rr++) {
      int qr = qt * 64 + wave * 16 + (lane >> 4) * 4 + rr;
      int col = h * 64 + ct * 16 + (lane & 15);
      float t = (accv[ct][rr] * am_av) / apc;
      x1q[((size_t)b * 1024 + qr) * 768 + col] = f2bf(rintf(clip87(t)));
    }
}

extern "C" void kernel_launch(void* const* d_in, const int* in_sizes, int n_in,
                              void* d_out, int out_size, void* d_ws, size_t ws_size,
                              hipStream_t stream) {
  const float* x0             = (const float*)d_in[0];
  const float* qkv_w          = (const float*)d_in[1];
  const float* qkv_b          = (const float*)d_in[2];
  const float* qkv_alpha      = (const float*)d_in[3];
  const float* qkv_act_alpha  = (const float*)d_in[4];
  const float* proj_w         = (const float*)d_in[5];
  const float* proj_b         = (const float*)d_in[6];
  const float* proj_alpha     = (const float*)d_in[7];
  const float* proj_act_alpha = (const float*)d_in[8];
  const float* nqw            = (const float*)d_in[9];
  const float* nqb            = (const float*)d_in[10];
  const float* nkw            = (const float*)d_in[11];
  const float* nkb            = (const float*)d_in[12];
  const float* q_alpha        = (const float*)d_in[13];
  const float* k_alpha        = (const float*)d_in[14];
  const float* v_alpha        = (const float*)d_in[15];
  const float* attn_alpha     = (const float*)d_in[16];
  float* out = (float*)d_out;

  char* ws = (char*)d_ws;
  size_t off = 0;
  auto alloc = [&](size_t bytes) -> void* {
    off = (off + 255) & ~(size_t)255;
    void* p = ws + off;
    off += bytes;
    return p;
  };
  float* scal = (float*)alloc(64);
  u16* wq     = (u16*)alloc((size_t)2304 * 768 * 2);
  u16* wp     = (u16*)alloc((size_t)768 * 768 * 2);
  float* biasi= (float*)alloc((size_t)2304 * 4);
  u16* x0q    = (u16*)alloc((size_t)4096 * 768 * 2);
  float* qkv  = (float*)alloc((size_t)4096 * 2304 * 4);
  u16* q2     = (u16*)alloc((size_t)48 * 1024 * 64 * 2);
  u16* k2     = (u16*)alloc((size_t)48 * 1024 * 64 * 2);
  u16* v2t    = (u16*)alloc((size_t)48 * 1024 * 64 * 2);
  u16* x1q    = (u16*)alloc((size_t)4096 * 768 * 2);

  k_scalars<<<1, 384, 0, stream>>>(qkv_act_alpha, proj_act_alpha, q_alpha, k_alpha,
                                   v_alpha, attn_alpha, scal);

  int totW = 2304 * 768 + 768 * 768 + 2304;
  k_quant_weights<<<(totW + 255) / 256, 256, 0, stream>>>(qkv_w, qkv_alpha, qkv_b,
                                                          proj_w, proj_alpha, scal,
                                                          wq, wp, biasi);

  k_quant_x0<<<(4096 * 768) / (256 * 8), 256, 0, stream>>>(x0, scal, x0q);

  k_gemm_bt<<<dim3(18, 32), 256, 0, stream>>>(x0q, wq, 4096, 2304, 768, qkv, biasi,
                                              nullptr, nullptr, scal, 0);

  k_quant_branches<<<dim3(4, 48), 256, 0, stream>>>(qkv, qkv_alpha, nqw, nqb, nkw, nkb,
                                                    scal, q2, k2, v2t);

  k_attn<<<dim3(16, 48), 256, 0, stream>>>(q2, k2, v2t, scal, x1q);

  k_gemm_bt<<<dim3(6, 32), 256, 0, stream>>>(x1q, wp, 4096, 768, 768, out, nullptr,
                                             proj_alpha, proj_b, scal, 1);
}

// Round 7
// 272.387 us; speedup vs baseline: 1.0176x; 1.0176x over previous
//
#include <hip/hip_runtime.h>

typedef unsigned short u16;
typedef unsigned int u32;
typedef __attribute__((ext_vector_type(8))) u16 u16x8;
typedef __attribute__((ext_vector_type(8))) __bf16 bf16x8;
typedef __attribute__((ext_vector_type(4))) float f32x4;

#define LOG2E_F 1.4426950408889634f

__device__ __forceinline__ u16 f2bf(float f) {
  // exact for the small integers we quantize to (|v| <= 8)
  return (u16)(__float_as_uint(f) >> 16);
}
__device__ __forceinline__ float clip87(float x) {
  return fminf(fmaxf(x, -8.0f), 7.0f);
}

// async global->LDS, 16B per lane; lptr must be wave-uniform (HW: lptr + lane*16)
typedef const __attribute__((address_space(1))) u32* gp32;
typedef __attribute__((address_space(3))) u32* lp32;
__device__ __forceinline__ void gl16(const void* g, void* l) {
  __builtin_amdgcn_global_load_lds((gp32)g, (lp32)l, 16, 0, 0);
}

// ---------------- scalar means + derived constants ----------------
// scal: [0]=a_in [1]=aq [2]=ak [3]=av [4]=am [5]=ap [6]=escale [7]=am*av
__global__ void k_scalars(const float* __restrict__ qkv_act_alpha,
                          const float* __restrict__ proj_act_alpha,
                          const float* __restrict__ q_alpha,
                          const float* __restrict__ k_alpha,
                          const float* __restrict__ v_alpha,
                          const float* __restrict__ attn_alpha,
                          float* __restrict__ scal) {
  int tid = threadIdx.x;
  int wave = tid >> 6, lane = tid & 63;
  if (wave < 6) {
    const float* src = nullptr; int n = 0;
    switch (wave) {
      case 0: src = qkv_act_alpha;  n = 768; break;
      case 1: src = q_alpha;        n = 12;  break;
      case 2: src = k_alpha;        n = 12;  break;
      case 3: src = v_alpha;        n = 12;  break;
      case 4: src = attn_alpha;     n = 12;  break;
      case 5: src = proj_act_alpha; n = 768; break;
    }
    double s = 0.0;
    for (int i = lane; i < n; i += 64) s += (double)src[i];
    s += __shfl_xor(s, 1);
    s += __shfl_xor(s, 2);
    s += __shfl_xor(s, 4);
    s += __shfl_xor(s, 8);
    s += __shfl_xor(s, 16);
    s += __shfl_xor(s, 32);
    if (lane == 0) scal[wave] = (float)(s / (double)n);
  }
  __syncthreads();
  if (tid == 0) {
    float aq = scal[1], ak = scal[2];
    float s_ = (0.125f * aq) * ak;   // head_scale * aq * ak
    scal[6] = LOG2E_F * s_;          // escale
    scal[7] = scal[4] * scal[3];     // am * av
  }
}

// ---------------- weight quantization ----------------
__global__ __launch_bounds__(256) void k_quant_weights(
    const float* __restrict__ qkv_w, const float* __restrict__ qkv_alpha,
    const float* __restrict__ qkv_b, const float* __restrict__ proj_w,
    const float* __restrict__ proj_alpha, const float* __restrict__ scal,
    u16* __restrict__ wq, u16* __restrict__ wp, float* __restrict__ biasi) {
  int idx = blockIdx.x * 256 + threadIdx.x;
  const int T1 = 2304 * 768, T2 = 768 * 768;
  if (idx < T1) {
    int o = idx / 768;
    wq[idx] = f2bf(rintf(clip87(qkv_w[idx] / qkv_alpha[o])));
  } else if (idx < T1 + T2) {
    int j = idx - T1;
    int o = j / 768;
    wp[j] = f2bf(rintf(clip87(proj_w[j] / proj_alpha[o])));
  } else if (idx < T1 + T2 + 2304) {
    int o = idx - T1 - T2;
    biasi[o] = truncf((qkv_b[o] / scal[0]) / qkv_alpha[o]);
  }
}

// ---------------- x0 activation quantization ----------------
__global__ __launch_bounds__(256) void k_quant_x0(const float* __restrict__ x0,
                                                  const float* __restrict__ scal,
                                                  u16* __restrict__ x0q) {
  int base = (blockIdx.x * 256 + threadIdx.x) * 8;
  float a = scal[0];
  f32x4 v0 = *(const f32x4*)&x0[base];
  f32x4 v1 = *(const f32x4*)&x0[base + 4];
  u16x8 o;
  #pragma unroll
  for (int j = 0; j < 4; j++) o[j] = f2bf(rintf(clip87(v0[j] / a)));
  #pragma unroll
  for (int j = 0; j < 4; j++) o[4 + j] = f2bf(rintf(clip87(v1[j] / a)));
  *(u16x8*)&x0q[base] = o;
}

// ---------------- generic C = A * B^T GEMM (bf16 MFMA, exact int) ----------------
// A: [M][K] bf16 row-major, Bt: [N][K] bf16 row-major. 128x128 tile, BK=32, 4 waves.
// m97 structure: global_load_lds width-16 staging into LINEAR [128][32] LDS.
// mode 0: Cout[row*N+col] = acc + bias[col]                (qkv)
// mode 1: Cout[row*N+col] = acc*palpha[col]*ap + pbias[col] (proj)
__global__ __launch_bounds__(256) void k_gemm_bt(
    const u16* __restrict__ A, const u16* __restrict__ Bt,
    int M, int N, int K, float* __restrict__ Cout,
    const float* __restrict__ bias, const float* __restrict__ palpha,
    const float* __restrict__ pbias, const float* __restrict__ scal, int mode) {
  __shared__ __align__(16) u16 lA[128 * 32];
  __shared__ __align__(16) u16 lB[128 * 32];
  int tid = threadIdx.x;
  int lane = tid & 63, wave = tid >> 6;
  int wr = wave >> 1, wc = wave & 1;
  int m0 = blockIdx.y * 128, n0 = blockIdx.x * 128;

  f32x4 acc[4][4];
  #pragma unroll
  for (int mi = 0; mi < 4; mi++)
    #pragma unroll
    for (int ni = 0; ni < 4; ni++) acc[mi][ni] = (f32x4){0.f, 0.f, 0.f, 0.f};

  // staging: wave w covers rows w*32..w*32+31 (two 1KB issues per matrix).
  // LDS offset of lane l within an issue: l*16B -> row=(l>>2), col u16=(l&3)*8
  int srow = wave * 32 + (lane >> 2);
  int scol = (lane & 3) * 8;
  const u16* gA = A + (size_t)(m0 + srow) * K + scol;
  const u16* gB = Bt + (size_t)(n0 + srow) * K + scol;
  u16* lA0 = lA + wave * 2 * 512;   // wave-uniform
  u16* lB0 = lB + wave * 2 * 512;
  const size_t rowskip = (size_t)16 * K;   // +16 rows for second issue

  int arow = wr * 64 + (lane & 15);
  int brow = wc * 64 + (lane & 15);
  int acol = (lane >> 4) * 8;

  for (int k0 = 0; k0 < K; k0 += 32) {
    gl16(gA + k0, lA0);
    gl16(gA + k0 + rowskip, lA0 + 512);
    gl16(gB + k0, lB0);
    gl16(gB + k0 + rowskip, lB0 + 512);
    __syncthreads();   // compiler drains vmcnt before barrier
    bf16x8 af[4], bf[4];
    #pragma unroll
    for (int mi = 0; mi < 4; mi++) af[mi] = *(const bf16x8*)&lA[(arow + mi * 16) * 32 + acol];
    #pragma unroll
    for (int ni = 0; ni < 4; ni++) bf[ni] = *(const bf16x8*)&lB[(brow + ni * 16) * 32 + acol];
    #pragma unroll
    for (int mi = 0; mi < 4; mi++)
      #pragma unroll
      for (int ni = 0; ni < 4; ni++)
        acc[mi][ni] = __builtin_amdgcn_mfma_f32_16x16x32_bf16(af[mi], bf[ni], acc[mi][ni], 0, 0, 0);
    __syncthreads();
  }

  int lrow = (lane >> 4) * 4, lcol = lane & 15;
  if (mode == 0) {
    #pragma unroll
    for (int mi = 0; mi < 4; mi++)
      #pragma unroll
      for (int ni = 0; ni < 4; ni++) {
        int col = n0 + wc * 64 + ni * 16 + lcol;
        float b = bias[col];
        #pragma unroll
        for (int rr = 0; rr < 4; rr++) {
          int row = m0 + wr * 64 + mi * 16 + lrow + rr;
          Cout[(size_t)row * N + col] = acc[mi][ni][rr] + b;
        }
      }
  } else {
    float ap = scal[5];
    #pragma unroll
    for (int mi = 0; mi < 4; mi++)
      #pragma unroll
      for (int ni = 0; ni < 4; ni++) {
        int col = n0 + wc * 64 + ni * 16 + lcol;
        float pa = palpha[col], pb = pbias[col];
        #pragma unroll
        for (int rr = 0; rr < 4; rr++) {
          int row = m0 + wr * 64 + mi * 16 + lrow + rr;
          Cout[(size_t)row * N + col] = (acc[mi][ni][rr] * pa) * ap + pb;
        }
      }
  }
}

// ---------------- q/k/v branch quantization ----------------
// grid: (4, 48) blocks of 256: n = bx*256+tid, bh = by. One thread per (b,h,n) row.
__global__ __launch_bounds__(256) void k_quant_branches(
    const float* __restrict__ qkv, const float* __restrict__ qkv_alpha,
    const float* __restrict__ nqw, const float* __restrict__ nqb,
    const float* __restrict__ nkw, const float* __restrict__ nkb,
    const float* __restrict__ scal, u16* __restrict__ q2, u16* __restrict__ k2,
    u16* __restrict__ v2t) {
  int n = blockIdx.x * 256 + threadIdx.x;
  int bh = blockIdx.y;
  int b = bh / 12, h = bh % 12;
  const float a_in = scal[0], aq = scal[1], ak = scal[2], av = scal[3];
  const float* row = qkv + (size_t)(b * 1024 + n) * 2304;

  float xq[64];
  // ---- q branch ----
  {
    #pragma unroll
    for (int j = 0; j < 16; j++) {
      f32x4 xv = *(const f32x4*)&row[h * 64 + j * 4];
      f32x4 av4 = *(const f32x4*)&qkv_alpha[h * 64 + j * 4];
      #pragma unroll
      for (int c = 0; c < 4; c++) xq[j * 4 + c] = xv[c] * av4[c];
    }
    int m = 0, v = 0;
    #pragma unroll
    for (int i = 0; i < 64; i++) {
      int xi = (int)xq[i];
      int dd = xi - m;
      m += (dd * (1024 / (i + 1))) >> 10;   // floor div by 1024
      v += dd * (xi - m);
    }
    float muf = (float)m;
    float den = sqrtf((float)v * 0.015625f) + 1e-5f;
    u16x8* dst = (u16x8*)(q2 + ((size_t)bh * 1024 + n) * 64);
    #pragma unroll
    for (int g = 0; g < 8; g++) {
      u16x8 t8;
      #pragma unroll
      for (int j = 0; j < 8; j++) {
        int d = g * 8 + j;
        float q1 = (xq[d] - muf) / den;
        float bw = nqb[d] / nqw[d];
        float t = (q1 + bw) * nqw[d] / aq;
        t8[j] = f2bf(rintf(clip87(t)));
      }
      dst[g] = t8;
    }
  }
  // ---- k branch ----
  {
    #pragma unroll
    for (int j = 0; j < 16; j++) {
      f32x4 xv = *(const f32x4*)&row[768 + h * 64 + j * 4];
      f32x4 av4 = *(const f32x4*)&qkv_alpha[768 + h * 64 + j * 4];
      #pragma unroll
      for (int c = 0; c < 4; c++) xq[j * 4 + c] = xv[c] * av4[c];
    }
    int m = 0, v = 0;
    #pragma unroll
    for (int i = 0; i < 64; i++) {
      int xi = (int)xq[i];
      int dd = xi - m;
      m += (dd * (1024 / (i + 1))) >> 10;
      v += dd * (xi - m);
    }
    float muf = (float)m;
    float den = sqrtf((float)v * 0.015625f) + 1e-5f;
    u16x8* dst = (u16x8*)(k2 + ((size_t)bh * 1024 + n) * 64);
    #pragma unroll
    for (int g = 0; g < 8; g++) {
      u16x8 t8;
      #pragma unroll
      for (int j = 0; j < 8; j++) {
        int d = g * 8 + j;
        float q1 = (xq[d] - muf) / den;
        float bw = nkb[d] / nkw[d];
        float t = (q1 + bw) * nkw[d] / ak;
        t8[j] = f2bf(rintf(clip87(t)));
      }
      dst[g] = t8;
    }
  }
  // ---- v branch (stored transposed: v2t[bh][d][n]) ----
  {
    #pragma unroll
    for (int j = 0; j < 16; j++) {
      f32x4 xv = *(const f32x4*)&row[1536 + h * 64 + j * 4];
      f32x4 av4 = *(const f32x4*)&qkv_alpha[1536 + h * 64 + j * 4];
      #pragma unroll
      for (int c = 0; c < 4; c++) {
        int d = j * 4 + c;
        float t = (xv[c] * (a_in * av4[c])) / av;
        v2t[((size_t)bh * 64 + d) * 1024 + n] = f2bf(rintf(clip87(t)));
      }
    }
  }
}

// ---------------- fused attention ----------------
// grid (16, 48): qt = bx (64 q rows), bh = by. 4 waves; wave w owns q rows w*16..w*16+15.
__global__ __launch_bounds__(256) void k_attn(
    const u16* __restrict__ q2, const u16* __restrict__ k2,
    const u16* __restrict__ v2t, const float* __restrict__ scal,
    u16* __restrict__ x1q) {
  __shared__ __align__(16) u16 lK[64 * 72];
  __shared__ __align__(16) u16 lV[64 * 72];
  __shared__ __align__(16) u16 lP[64 * 72];
  __shared__ float rs_lds[64];
  int tid = threadIdx.x, lane = tid & 63, wave = tid >> 6;
  int qt = blockIdx.x, bh = blockIdx.y;
  const float escale = scal[6], am = scal[4], am_av = scal[7], apc = scal[5];

  // q fragments (persist): rows = bh*1024 + qt*64 + wave*16 + (lane&15)
  size_t qrow = (size_t)bh * 1024 + qt * 64 + wave * 16 + (lane & 15);
  bf16x8 qf0 = *(const bf16x8*)(q2 + qrow * 64 + (lane >> 4) * 8);
  bf16x8 qf1 = *(const bf16x8*)(q2 + qrow * 64 + 32 + (lane >> 4) * 8);

  const u16* k2b = k2 + (size_t)bh * 1024 * 64;
  const u16* v2b = v2t + (size_t)bh * 64 * 1024;
  int sr = tid >> 2, sc = (tid & 3) * 16;

  // ---- pass 1: row sums of attn_exp (f32 per-kt partial, f64 across kt) ----
  double rsum[4] = {0.0, 0.0, 0.0, 0.0};
  for (int kt = 0; kt < 16; kt++) {
    const u16* src = k2b + (size_t)(kt * 64 + sr) * 64 + sc;
    *(u16x8*)&lK[sr * 72 + sc]     = *(const u16x8*)src;
    *(u16x8*)&lK[sr * 72 + sc + 8] = *(const u16x8*)(src + 8);
    __syncthreads();
    float part[4] = {0.f, 0.f, 0.f, 0.f};
    #pragma unroll
    for (int ct = 0; ct < 4; ct++) {
      bf16x8 kf0 = *(const bf16x8*)&lK[(ct * 16 + (lane & 15)) * 72 + (lane >> 4) * 8];
      bf16x8 kf1 = *(const bf16x8*)&lK[(ct * 16 + (lane & 15)) * 72 + 32 + (lane >> 4) * 8];
      f32x4 s = {0.f, 0.f, 0.f, 0.f};
      s = __builtin_amdgcn_mfma_f32_16x16x32_bf16(qf0, kf0, s, 0, 0, 0);
      s = __builtin_amdgcn_mfma_f32_16x16x32_bf16(qf1, kf1, s, 0, 0, 0);
      #pragma unroll
      for (int rr = 0; rr < 4; rr++) {
        float e = escale * s[rr];
        float f = floorf(e);
        float pe = ldexpf(1.0f + (e - f), (int)f);  // exact 2^f scaling
        part[rr] += pe;
      }
    }
    #pragma unroll
    for (int rr = 0; rr < 4; rr++) rsum[rr] += (double)part[rr];
    __syncthreads();
  }
  #pragma unroll
  for (int rr = 0; rr < 4; rr++) {
    double s = rsum[rr];
    s += __shfl_xor(s, 1);
    s += __shfl_xor(s, 2);
    s += __shfl_xor(s, 4);
    s += __shfl_xor(s, 8);
    if ((lane & 15) == 0) rs_lds[wave * 16 + (lane >> 4) * 4 + rr] = (float)s;
  }
  __syncthreads();
  float fac[4];
  #pragma unroll
  for (int rr = 0; rr < 4; rr++)
    fac[rr] = 1.0f / (rs_lds[wave * 16 + (lane >> 4) * 4 + rr] * am);

  // ---- pass 2: recompute S (bitwise identical), quantize attn, PV GEMM ----
  f32x4 accv[4];
  #pragma unroll
  for (int ct = 0; ct < 4; ct++) accv[ct] = (f32x4){0.f, 0.f, 0.f, 0.f};

  for (int kt = 0; kt < 16; kt++) {
    const u16* srcK = k2b + (size_t)(kt * 64 + sr) * 64 + sc;
    *(u16x8*)&lK[sr * 72 + sc]     = *(const u16x8*)srcK;
    *(u16x8*)&lK[sr * 72 + sc + 8] = *(const u16x8*)(srcK + 8);
    const u16* srcV = v2b + (size_t)sr * 1024 + kt * 64 + sc;
    *(u16x8*)&lV[sr * 72 + sc]     = *(const u16x8*)srcV;
    *(u16x8*)&lV[sr * 72 + sc + 8] = *(const u16x8*)(srcV + 8);
    __syncthreads();
    #pragma unroll
    for (int ct = 0; ct < 4; ct++) {
      bf16x8 kf0 = *(const bf16x8*)&lK[(ct * 16 + (lane & 15)) * 72 + (lane >> 4) * 8];
      bf16x8 kf1 = *(const bf16x8*)&lK[(ct * 16 + (lane & 15)) * 72 + 32 + (lane >> 4) * 8];
      f32x4 s = {0.f, 0.f, 0.f, 0.f};
      s = __builtin_amdgcn_mfma_f32_16x16x32_bf16(qf0, kf0, s, 0, 0, 0);
      s = __builtin_amdgcn_mfma_f32_16x16x32_bf16(qf1, kf1, s, 0, 0, 0);
      #pragma unroll
      for (int rr = 0; rr < 4; rr++) {
        float e = escale * s[rr];
        float f = floorf(e);
        float pe = ldexpf(1.0f + (e - f), (int)f);
        float a2 = rintf(fminf(pe * fac[rr], 7.0f));   // pe*fac >= 0, no lower clip
        lP[(wave * 16 + (lane >> 4) * 4 + rr) * 72 + ct * 16 + (lane & 15)] = f2bf(a2);
      }
    }
    __syncthreads();
    bf16x8 pf0 = *(const bf16x8*)&lP[(wave * 16 + (lane & 15)) * 72 + (lane >> 4) * 8];
    bf16x8 pf1 = *(const bf16x8*)&lP[(wave * 16 + (lane & 15)) * 72 + 32 + (lane >> 4) * 8];
    #pragma unroll
    for (int ct = 0; ct < 4; ct++) {
      bf16x8 vf0 = *(const bf16x8*)&lV[(ct * 16 + (lane & 15)) * 72 + (lane >> 4) * 8];
      bf16x8 vf1 = *(const bf16x8*)&lV[(ct * 16 + (lane & 15)) * 72 + 32 + (lane >> 4) * 8];
      accv[ct] = __builtin_amdgcn_mfma_f32_16x16x32_bf16(pf0, vf0, accv[ct], 0, 0, 0);
      accv[ct] = __builtin_amdgcn_mfma_f32_16x16x32_bf16(pf1, vf1, accv[ct], 0, 0, 0);
    }
    __syncthreads();
  }

  // epilogue: x1_2b quantization, write (B,N,C) layout
  int b = bh / 12, h = bh % 12;
  #pragma unroll
  for (int ct = 0; ct < 4; ct++)
    #pragma unroll
    for (int rr = 0; rr < 4; rr++) {
      int qr = qt * 64 + wave * 16 + (lane >> 4) * 4 + rr;
      int col = h * 64 + ct * 16 + (lane & 15);
      float t = (accv[ct][rr] * am_av) / apc;
      x1q[((size_t)b * 1024 + qr) * 768 + col] = f2bf(rintf(clip87(t)));
    }
}

extern "C" void kernel_launch(void* const* d_in, const int* in_sizes, int n_in,
                              void* d_out, int out_size, void* d_ws, size_t ws_size,
                              hipStream_t stream) {
  const float* x0             = (const float*)d_in[0];
  const float* qkv_w          = (const float*)d_in[1];
  const float* qkv_b          = (const float*)d_in[2];
  const float* qkv_alpha      = (const float*)d_in[3];
  const float* qkv_act_alpha  = (const float*)d_in[4];
  const float* proj_w         = (const float*)d_in[5];
  const float* proj_b         = (const float*)d_in[6];
  const float* proj_alpha     = (const float*)d_in[7];
  const float* proj_act_alpha = (const float*)d_in[8];
  const float* nqw            = (const float*)d_in[9];
  const float* nqb            = (const float*)d_in[10];
  const float* nkw            = (const float*)d_in[11];
  const float* nkb            = (const float*)d_in[12];
  const float* q_alpha        = (const float*)d_in[13];
  const float* k_alpha        = (const float*)d_in[14];
  const float* v_alpha        = (const float*)d_in[15];
  const float* attn_alpha     = (const float*)d_in[16];
  float* out = (float*)d_out;

  char* ws = (char*)d_ws;
  size_t off = 0;
  auto alloc = [&](size_t bytes) -> void* {
    off = (off + 255) & ~(size_t)255;
    void* p = ws + off;
    off += bytes;
    return p;
  };
  float* scal = (float*)alloc(64);
  u16* wq     = (u16*)alloc((size_t)2304 * 768 * 2);
  u16* wp     = (u16*)alloc((size_t)768 * 768 * 2);
  float* biasi= (float*)alloc((size_t)2304 * 4);
  u16* x0q    = (u16*)alloc((size_t)4096 * 768 * 2);
  float* qkv  = (float*)alloc((size_t)4096 * 2304 * 4);
  u16* q2     = (u16*)alloc((size_t)48 * 1024 * 64 * 2);
  u16* k2     = (u16*)alloc((size_t)48 * 1024 * 64 * 2);
  u16* v2t    = (u16*)alloc((size_t)48 * 1024 * 64 * 2);
  u16* x1q    = (u16*)alloc((size_t)4096 * 768 * 2);

  k_scalars<<<1, 384, 0, stream>>>(qkv_act_alpha, proj_act_alpha, q_alpha, k_alpha,
                                   v_alpha, attn_alpha, scal);

  int totW = 2304 * 768 + 768 * 768 + 2304;
  k_quant_weights<<<(totW + 255) / 256, 256, 0, stream>>>(qkv_w, qkv_alpha, qkv_b,
                                                          proj_w, proj_alpha, scal,
                                                          wq, wp, biasi);

  k_quant_x0<<<(4096 * 768) / (256 * 8), 256, 0, stream>>>(x0, scal, x0q);

  k_gemm_bt<<<dim3(18, 32), 256, 0, stream>>>(x0q, wq, 4096, 2304, 768, qkv, biasi,
                                              nullptr, nullptr, scal, 0);

  k_quant_branches<<<dim3(4, 48), 256, 0, stream>>>(qkv, qkv_alpha, nqw, nqb, nkw, nkb,
                                                    scal, q2, k2, v2t);

  k_attn<<<dim3(16, 48), 256, 0, stream>>>(q2, k2, v2t, scal, x1q);

  k_gemm_bt<<<dim3(6, 32), 256, 0, stream>>>(x1q, wp, 4096, 768, 768, out, nullptr,
                                             proj_alpha, proj_b, scal, 1);
}

// Round 8
// 228.903 us; speedup vs baseline: 1.2109x; 1.1900x over previous
//
#include <hip/hip_runtime.h>

typedef unsigned short u16;
typedef unsigned int u32;
typedef __attribute__((ext_vector_type(8))) u16 u16x8;
typedef __attribute__((ext_vector_type(8))) __bf16 bf16x8;
typedef __attribute__((ext_vector_type(4))) float f32x4;

#define LOG2E_F 1.4426950408889634f

__device__ __forceinline__ u16 f2bf(float f) {
  return (u16)(__float_as_uint(f) >> 16);
}
__device__ __forceinline__ float clip87(float x) {
  return fminf(fmaxf(x, -8.0f), 7.0f);
}

// async global->LDS, 16B per lane; lptr must be wave-uniform (HW: lptr + lane*16)
typedef const __attribute__((address_space(1))) u32* gp32;
typedef __attribute__((address_space(3))) u32* lp32;
__device__ __forceinline__ void gl16(const void* g, void* l) {
  __builtin_amdgcn_global_load_lds((gp32)g, (lp32)l, 16, 0, 0);
}

// ---------------- scalar means + derived constants ----------------
// scal: [0]=a_in [1]=aq [2]=ak [3]=av [4]=am [5]=ap [6]=escale [7]=am*av
__global__ void k_scalars(const float* __restrict__ qkv_act_alpha,
                          const float* __restrict__ proj_act_alpha,
                          const float* __restrict__ q_alpha,
                          const float* __restrict__ k_alpha,
                          const float* __restrict__ v_alpha,
                          const float* __restrict__ attn_alpha,
                          float* __restrict__ scal) {
  int tid = threadIdx.x;
  int wave = tid >> 6, lane = tid & 63;
  if (wave < 6) {
    const float* src = nullptr; int n = 0;
    switch (wave) {
      case 0: src = qkv_act_alpha;  n = 768; break;
      case 1: src = q_alpha;        n = 12;  break;
      case 2: src = k_alpha;        n = 12;  break;
      case 3: src = v_alpha;        n = 12;  break;
      case 4: src = attn_alpha;     n = 12;  break;
      case 5: src = proj_act_alpha; n = 768; break;
    }
    double s = 0.0;
    for (int i = lane; i < n; i += 64) s += (double)src[i];
    s += __shfl_xor(s, 1);
    s += __shfl_xor(s, 2);
    s += __shfl_xor(s, 4);
    s += __shfl_xor(s, 8);
    s += __shfl_xor(s, 16);
    s += __shfl_xor(s, 32);
    if (lane == 0) scal[wave] = (float)(s / (double)n);
  }
  __syncthreads();
  if (tid == 0) {
    float aq = scal[1], ak = scal[2];
    float s_ = (0.125f * aq) * ak;   // head_scale * aq * ak
    scal[6] = LOG2E_F * s_;          // escale
    scal[7] = scal[4] * scal[3];     // am * av
  }
}

// ---------------- weight quantization ----------------
__global__ __launch_bounds__(256) void k_quant_weights(
    const float* __restrict__ qkv_w, const float* __restrict__ qkv_alpha,
    const float* __restrict__ qkv_b, const float* __restrict__ proj_w,
    const float* __restrict__ proj_alpha, const float* __restrict__ scal,
    u16* __restrict__ wq, u16* __restrict__ wp, float* __restrict__ biasi) {
  int idx = blockIdx.x * 256 + threadIdx.x;
  const int T1 = 2304 * 768, T2 = 768 * 768;
  if (idx < T1) {
    int o = idx / 768;
    wq[idx] = f2bf(rintf(clip87(qkv_w[idx] / qkv_alpha[o])));
  } else if (idx < T1 + T2) {
    int j = idx - T1;
    int o = j / 768;
    wp[j] = f2bf(rintf(clip87(proj_w[j] / proj_alpha[o])));
  } else if (idx < T1 + T2 + 2304) {
    int o = idx - T1 - T2;
    biasi[o] = truncf((qkv_b[o] / scal[0]) / qkv_alpha[o]);
  }
}

// ---------------- x0 activation quantization ----------------
__global__ __launch_bounds__(256) void k_quant_x0(const float* __restrict__ x0,
                                                  const float* __restrict__ scal,
                                                  u16* __restrict__ x0q) {
  int base = (blockIdx.x * 256 + threadIdx.x) * 8;
  float a = scal[0];
  f32x4 v0 = *(const f32x4*)&x0[base];
  f32x4 v1 = *(const f32x4*)&x0[base + 4];
  u16x8 o;
  #pragma unroll
  for (int j = 0; j < 4; j++) o[j] = f2bf(rintf(clip87(v0[j] / a)));
  #pragma unroll
  for (int j = 0; j < 4; j++) o[4 + j] = f2bf(rintf(clip87(v1[j] / a)));
  *(u16x8*)&x0q[base] = o;
}

// ---------------- qkv GEMM with FUSED branch quantization ----------------
// A=x0q [4096][768], Bt=wq [2304][768]. 128x128 tile, BK=32, 4 waves.
// grid (18, 32): bx = col-tile -> branch = bx/6 (0=q,1=k,2=v), head pair hp = bx%6.
// Epilogue: stage (acc+biasi) into LDS f32 tile, then per-thread serial
// mean/var recurrence + quant for q/k rows; transpose+quant for v columns.
// Math is op-for-op identical to the old qkv-write + k_quant_branches path.
__global__ __launch_bounds__(256) void k_gemm_qkv(
    const u16* __restrict__ A, const u16* __restrict__ Bt,
    const float* __restrict__ biasi, const float* __restrict__ qkv_alpha,
    const float* __restrict__ nqw, const float* __restrict__ nqb,
    const float* __restrict__ nkw, const float* __restrict__ nkb,
    const float* __restrict__ scal,
    u16* __restrict__ q2, u16* __restrict__ k2, u16* __restrict__ v2t) {
  const int K = 768;
  __shared__ __align__(16) float xt[128 * 129];   // 66KB; aliases staging LDS
  u16* lA = (u16*)xt;                              // 8KB
  u16* lB = ((u16*)xt) + 128 * 32;                 // 8KB
  int tid = threadIdx.x;
  int lane = tid & 63, wave = tid >> 6;
  int wr = wave >> 1, wc = wave & 1;
  int m0 = blockIdx.y * 128, n0 = blockIdx.x * 128;

  f32x4 acc[4][4];
  #pragma unroll
  for (int mi = 0; mi < 4; mi++)
    #pragma unroll
    for (int ni = 0; ni < 4; ni++) acc[mi][ni] = (f32x4){0.f, 0.f, 0.f, 0.f};

  int srow = wave * 32 + (lane >> 2);
  int scol = (lane & 3) * 8;
  const u16* gA = A + (size_t)(m0 + srow) * K + scol;
  const u16* gB = Bt + (size_t)(n0 + srow) * K + scol;
  u16* lA0 = lA + wave * 2 * 512;
  u16* lB0 = lB + wave * 2 * 512;
  const size_t rowskip = (size_t)16 * K;

  int arow = wr * 64 + (lane & 15);
  int brow = wc * 64 + (lane & 15);
  int acol = (lane >> 4) * 8;

  for (int k0 = 0; k0 < K; k0 += 32) {
    gl16(gA + k0, lA0);
    gl16(gA + k0 + rowskip, lA0 + 512);
    gl16(gB + k0, lB0);
    gl16(gB + k0 + rowskip, lB0 + 512);
    __syncthreads();
    bf16x8 af[4], bf[4];
    #pragma unroll
    for (int mi = 0; mi < 4; mi++) af[mi] = *(const bf16x8*)&lA[(arow + mi * 16) * 32 + acol];
    #pragma unroll
    for (int ni = 0; ni < 4; ni++) bf[ni] = *(const bf16x8*)&lB[(brow + ni * 16) * 32 + acol];
    #pragma unroll
    for (int mi = 0; mi < 4; mi++)
      #pragma unroll
      for (int ni = 0; ni < 4; ni++)
        acc[mi][ni] = __builtin_amdgcn_mfma_f32_16x16x32_bf16(af[mi], bf[ni], acc[mi][ni], 0, 0, 0);
    __syncthreads();
  }

  // ---- phase 1: raw qkv tile (acc + bias) -> LDS ----
  int lrow = (lane >> 4) * 4, lcol = lane & 15;
  #pragma unroll
  for (int mi = 0; mi < 4; mi++)
    #pragma unroll
    for (int ni = 0; ni < 4; ni++) {
      int c = wc * 64 + ni * 16 + lcol;
      float bs = biasi[n0 + c];
      #pragma unroll
      for (int rr = 0; rr < 4; rr++) {
        int r = wr * 64 + mi * 16 + lrow + rr;
        xt[r * 129 + c] = acc[mi][ni][rr] + bs;
      }
    }
  __syncthreads();

  // ---- phase 2: branch quantization ----
  int branch = blockIdx.x / 6, hp = blockIdx.x % 6;
  int b = m0 >> 10, nb = m0 & 1023;
  if (branch == 2) {
    // v: thread owns one column (head h, dim d); transpose-write v2t[bh][d][n]
    int c = tid & 127, hf = tid >> 7;
    int h = hp * 2 + (c >> 6), d = c & 63;
    float av = scal[3];
    float coefv = scal[0] * qkv_alpha[1536 + h * 64 + d];
    u16* dst = v2t + ((size_t)(b * 12 + h) * 64 + d) * 1024 + nb + hf * 64;
    #pragma unroll
    for (int g = 0; g < 8; g++) {
      u16x8 t8;
      #pragma unroll
      for (int j = 0; j < 8; j++) {
        float val = xt[(hf * 64 + g * 8 + j) * 129 + c];
        t8[j] = f2bf(rintf(clip87((val * coefv) / av)));
      }
      *(u16x8*)(dst + g * 8) = t8;
    }
  } else {
    // q/k: thread owns one row of one head; serial int mean/var recurrence
    int r = tid & 127, hs = tid >> 7;
    int h = hp * 2 + hs;
    const float* alph = qkv_alpha + branch * 768 + h * 64;
    const float* wv = branch == 0 ? nqw : nkw;
    const float* bv = branch == 0 ? nqb : nkb;
    float as = branch == 0 ? scal[1] : scal[2];
    float xq[64];
    #pragma unroll
    for (int d = 0; d < 64; d++) xq[d] = xt[r * 129 + hs * 64 + d] * alph[d];
    int m = 0, v = 0;
    #pragma unroll
    for (int i = 0; i < 64; i++) {
      int xi = (int)xq[i];
      int dd = xi - m;
      m += (dd * (1024 / (i + 1))) >> 10;   // floor div by 1024
      v += dd * (xi - m);
    }
    float muf = (float)m;
    float den = sqrtf((float)v * 0.015625f) + 1e-5f;
    u16* outp = (branch == 0 ? q2 : k2) + ((size_t)(b * 12 + h) * 1024 + nb + r) * 64;
    #pragma unroll
    for (int g = 0; g < 8; g++) {
      u16x8 t8;
      #pragma unroll
      for (int j = 0; j < 8; j++) {
        int d = g * 8 + j;
        float q1 = (xq[d] - muf) / den;
        float bw = bv[d] / wv[d];
        float t = (q1 + bw) * wv[d] / as;
        t8[j] = f2bf(rintf(clip87(t)));
      }
      *(u16x8*)(outp + g * 8) = t8;
    }
  }
}

// ---------------- proj GEMM: C = A * B^T, fused scale+bias epilogue ----------------
__global__ __launch_bounds__(256) void k_gemm_proj(
    const u16* __restrict__ A, const u16* __restrict__ Bt,
    float* __restrict__ Cout, const float* __restrict__ palpha,
    const float* __restrict__ pbias, const float* __restrict__ scal) {
  const int K = 768, N = 768;
  __shared__ __align__(16) u16 lA[128 * 32];
  __shared__ __align__(16) u16 lB[128 * 32];
  int tid = threadIdx.x;
  int lane = tid & 63, wave = tid >> 6;
  int wr = wave >> 1, wc = wave & 1;
  int m0 = blockIdx.y * 128, n0 = blockIdx.x * 128;

  f32x4 acc[4][4];
  #pragma unroll
  for (int mi = 0; mi < 4; mi++)
    #pragma unroll
    for (int ni = 0; ni < 4; ni++) acc[mi][ni] = (f32x4){0.f, 0.f, 0.f, 0.f};

  int srow = wave * 32 + (lane >> 2);
  int scol = (lane & 3) * 8;
  const u16* gA = A + (size_t)(m0 + srow) * K + scol;
  const u16* gB = Bt + (size_t)(n0 + srow) * K + scol;
  u16* lA0 = lA + wave * 2 * 512;
  u16* lB0 = lB + wave * 2 * 512;
  const size_t rowskip = (size_t)16 * K;

  int arow = wr * 64 + (lane & 15);
  int brow = wc * 64 + (lane & 15);
  int acol = (lane >> 4) * 8;

  for (int k0 = 0; k0 < K; k0 += 32) {
    gl16(gA + k0, lA0);
    gl16(gA + k0 + rowskip, lA0 + 512);
    gl16(gB + k0, lB0);
    gl16(gB + k0 + rowskip, lB0 + 512);
    __syncthreads();
    bf16x8 af[4], bf[4];
    #pragma unroll
    for (int mi = 0; mi < 4; mi++) af[mi] = *(const bf16x8*)&lA[(arow + mi * 16) * 32 + acol];
    #pragma unroll
    for (int ni = 0; ni < 4; ni++) bf[ni] = *(const bf16x8*)&lB[(brow + ni * 16) * 32 + acol];
    #pragma unroll
    for (int mi = 0; mi < 4; mi++)
      #pragma unroll
      for (int ni = 0; ni < 4; ni++)
        acc[mi][ni] = __builtin_amdgcn_mfma_f32_16x16x32_bf16(af[mi], bf[ni], acc[mi][ni], 0, 0, 0);
    __syncthreads();
  }

  int lrow = (lane >> 4) * 4, lcol = lane & 15;
  float ap = scal[5];
  #pragma unroll
  for (int mi = 0; mi < 4; mi++)
    #pragma unroll
    for (int ni = 0; ni < 4; ni++) {
      int col = n0 + wc * 64 + ni * 16 + lcol;
      float pa = palpha[col], pb = pbias[col];
      #pragma unroll
      for (int rr = 0; rr < 4; rr++) {
        int row = m0 + wr * 64 + mi * 16 + lrow + rr;
        Cout[(size_t)row * N + col] = (acc[mi][ni][rr] * pa) * ap + pb;
      }
    }
}

// ---------------- fused attention ----------------
// grid (16, 48): qt = bx (64 q rows), bh = by. 4 waves; wave w owns q rows w*16..w*16+15.
__global__ __launch_bounds__(256) void k_attn(
    const u16* __restrict__ q2, const u16* __restrict__ k2,
    const u16* __restrict__ v2t, const float* __restrict__ scal,
    u16* __restrict__ x1q) {
  __shared__ __align__(16) u16 lK[64 * 72];
  __shared__ __align__(16) u16 lV[64 * 72];
  __shared__ __align__(16) u16 lP[64 * 72];
  __shared__ float rs_lds[64];
  int tid = threadIdx.x, lane = tid & 63, wave = tid >> 6;
  int qt = blockIdx.x, bh = blockIdx.y;
  const float escale = scal[6], am = scal[4], am_av = scal[7], apc = scal[5];

  size_t qrow = (size_t)bh * 1024 + qt * 64 + wave * 16 + (lane & 15);
  bf16x8 qf0 = *(const bf16x8*)(q2 + qrow * 64 + (lane >> 4) * 8);
  bf16x8 qf1 = *(const bf16x8*)(q2 + qrow * 64 + 32 + (lane >> 4) * 8);

  const u16* k2b = k2 + (size_t)bh * 1024 * 64;
  const u16* v2b = v2t + (size_t)bh * 64 * 1024;
  int sr = tid >> 2, sc = (tid & 3) * 16;

  // ---- pass 1: row sums of attn_exp (f32 per-kt partial, f64 across kt) ----
  double rsum[4] = {0.0, 0.0, 0.0, 0.0};
  for (int kt = 0; kt < 16; kt++) {
    const u16* src = k2b + (size_t)(kt * 64 + sr) * 64 + sc;
    *(u16x8*)&lK[sr * 72 + sc]     = *(const u16x8*)src;
    *(u16x8*)&lK[sr * 72 + sc + 8] = *(const u16x8*)(src + 8);
    __syncthreads();
    float part[4] = {0.f, 0.f, 0.f, 0.f};
    #pragma unroll
    for (int ct = 0; ct < 4; ct++) {
      bf16x8 kf0 = *(const bf16x8*)&lK[(ct * 16 + (lane & 15)) * 72 + (lane >> 4) * 8];
      bf16x8 kf1 = *(const bf16x8*)&lK[(ct * 16 + (lane & 15)) * 72 + 32 + (lane >> 4) * 8];
      f32x4 s = {0.f, 0.f, 0.f, 0.f};
      s = __builtin_amdgcn_mfma_f32_16x16x32_bf16(qf0, kf0, s, 0, 0, 0);
      s = __builtin_amdgcn_mfma_f32_16x16x32_bf16(qf1, kf1, s, 0, 0, 0);
      #pragma unroll
      for (int rr = 0; rr < 4; rr++) {
        float e = escale * s[rr];
        float f = floorf(e);
        float pe = ldexpf(1.0f + (e - f), (int)f);  // exact 2^f scaling
        part[rr] += pe;
      }
    }
    #pragma unroll
    for (int rr = 0; rr < 4; rr++) rsum[rr] += (double)part[rr];
    __syncthreads();
  }
  #pragma unroll
  for (int rr = 0; rr < 4; rr++) {
    double s = rsum[rr];
    s += __shfl_xor(s, 1);
    s += __shfl_xor(s, 2);
    s += __shfl_xor(s, 4);
    s += __shfl_xor(s, 8);
    if ((lane & 15) == 0) rs_lds[wave * 16 + (lane >> 4) * 4 + rr] = (float)s;
  }
  __syncthreads();
  float fac[4];
  #pragma unroll
  for (int rr = 0; rr < 4; rr++)
    fac[rr] = 1.0f / (rs_lds[wave * 16 + (lane >> 4) * 4 + rr] * am);

  // ---- pass 2: recompute S (bitwise identical), quantize attn, PV GEMM ----
  f32x4 accv[4];
  #pragma unroll
  for (int ct = 0; ct < 4; ct++) accv[ct] = (f32x4){0.f, 0.f, 0.f, 0.f};

  for (int kt = 0; kt < 16; kt++) {
    const u16* srcK = k2b + (size_t)(kt * 64 + sr) * 64 + sc;
    *(u16x8*)&lK[sr * 72 + sc]     = *(const u16x8*)srcK;
    *(u16x8*)&lK[sr * 72 + sc + 8] = *(const u16x8*)(srcK + 8);
    const u16* srcV = v2b + (size_t)sr * 1024 + kt * 64 + sc;
    *(u16x8*)&lV[sr * 72 + sc]     = *(const u16x8*)srcV;
    *(u16x8*)&lV[sr * 72 + sc + 8] = *(const u16x8*)(srcV + 8);
    __syncthreads();
    #pragma unroll
    for (int ct = 0; ct < 4; ct++) {
      bf16x8 kf0 = *(const bf16x8*)&lK[(ct * 16 + (lane & 15)) * 72 + (lane >> 4) * 8];
      bf16x8 kf1 = *(const bf16x8*)&lK[(ct * 16 + (lane & 15)) * 72 + 32 + (lane >> 4) * 8];
      f32x4 s = {0.f, 0.f, 0.f, 0.f};
      s = __builtin_amdgcn_mfma_f32_16x16x32_bf16(qf0, kf0, s, 0, 0, 0);
      s = __builtin_amdgcn_mfma_f32_16x16x32_bf16(qf1, kf1, s, 0, 0, 0);
      #pragma unroll
      for (int rr = 0; rr < 4; rr++) {
        float e = escale * s[rr];
        float f = floorf(e);
        float pe = ldexpf(1.0f + (e - f), (int)f);
        float a2 = rintf(fminf(pe * fac[rr], 7.0f));
        lP[(wave * 16 + (lane >> 4) * 4 + rr) * 72 + ct * 16 + (lane & 15)] = f2bf(a2);
      }
    }
    __syncthreads();
    bf16x8 pf0 = *(const bf16x8*)&lP[(wave * 16 + (lane & 15)) * 72 + (lane >> 4) * 8];
    bf16x8 pf1 = *(const bf16x8*)&lP[(wave * 16 + (lane & 15)) * 72 + 32 + (lane >> 4) * 8];
    #pragma unroll
    for (int ct = 0; ct < 4; ct++) {
      bf16x8 vf0 = *(const bf16x8*)&lV[(ct * 16 + (lane & 15)) * 72 + (lane >> 4) * 8];
      bf16x8 vf1 = *(const bf16x8*)&lV[(ct * 16 + (lane & 15)) * 72 + 32 + (lane >> 4) * 8];
      accv[ct] = __builtin_amdgcn_mfma_f32_16x16x32_bf16(pf0, vf0, accv[ct], 0, 0, 0);
      accv[ct] = __builtin_amdgcn_mfma_f32_16x16x32_bf16(pf1, vf1, accv[ct], 0, 0, 0);
    }
    __syncthreads();
  }

  int b = bh / 12, h = bh % 12;
  #pragma unroll
  for (int ct = 0; ct < 4; ct++)
    #pragma unroll
    for (int rr = 0; rr < 4; rr++) {
      int qr = qt * 64 + wave * 16 + (lane >> 4) * 4 + rr;
      int col = h * 64 + ct * 16 + (lane & 15);
      float t = (accv[ct][rr] * am_av) / apc;
      x1q[((size_t)b * 1024 + qr) * 768 + col] = f2bf(rintf(clip87(t)));
    }
}

extern "C" void kernel_launch(void* const* d_in, const int* in_sizes, int n_in,
                              void* d_out, int out_size, void* d_ws, size_t ws_size,
                              hipStream_t stream) {
  const float* x0             = (const float*)d_in[0];
  const float* qkv_w          = (const float*)d_in[1];
  const float* qkv_b          = (const float*)d_in[2];
  const float* qkv_alpha      = (const float*)d_in[3];
  const float* qkv_act_alpha  = (const float*)d_in[4];
  const float* proj_w         = (const float*)d_in[5];
  const float* proj_b         = (const float*)d_in[6];
  const float* proj_alpha     = (const float*)d_in[7];
  const float* proj_act_alpha = (const float*)d_in[8];
  const float* nqw            = (const float*)d_in[9];
  const float* nqb            = (const float*)d_in[10];
  const float* nkw            = (const float*)d_in[11];
  const float* nkb            = (const float*)d_in[12];
  const float* q_alpha        = (const float*)d_in[13];
  const float* k_alpha        = (const float*)d_in[14];
  const float* v_alpha        = (const float*)d_in[15];
  const float* attn_alpha     = (const float*)d_in[16];
  float* out = (float*)d_out;

  char* ws = (char*)d_ws;
  size_t off = 0;
  auto alloc = [&](size_t bytes) -> void* {
    off = (off + 255) & ~(size_t)255;
    void* p = ws + off;
    off += bytes;
    return p;
  };
  float* scal = (float*)alloc(64);
  u16* wq     = (u16*)alloc((size_t)2304 * 768 * 2);
  u16* wp     = (u16*)alloc((size_t)768 * 768 * 2);
  float* biasi= (float*)alloc((size_t)2304 * 4);
  u16* x0q    = (u16*)alloc((size_t)4096 * 768 * 2);
  u16* q2     = (u16*)alloc((size_t)48 * 1024 * 64 * 2);
  u16* k2     = (u16*)alloc((size_t)48 * 1024 * 64 * 2);
  u16* v2t    = (u16*)alloc((size_t)48 * 1024 * 64 * 2);
  u16* x1q    = (u16*)alloc((size_t)4096 * 768 * 2);

  k_scalars<<<1, 384, 0, stream>>>(qkv_act_alpha, proj_act_alpha, q_alpha, k_alpha,
                                   v_alpha, attn_alpha, scal);

  int totW = 2304 * 768 + 768 * 768 + 2304;
  k_quant_weights<<<(totW + 255) / 256, 256, 0, stream>>>(qkv_w, qkv_alpha, qkv_b,
                                                          proj_w, proj_alpha, scal,
                                                          wq, wp, biasi);

  k_quant_x0<<<(4096 * 768) / (256 * 8), 256, 0, stream>>>(x0, scal, x0q);

  k_gemm_qkv<<<dim3(18, 32), 256, 0, stream>>>(x0q, wq, biasi, qkv_alpha,
                                               nqw, nqb, nkw, nkb, scal,
                                               q2, k2, v2t);

  k_attn<<<dim3(16, 48), 256, 0, stream>>>(q2, k2, v2t, scal, x1q);

  k_gemm_proj<<<dim3(6, 32), 256, 0, stream>>>(x1q, wp, out, proj_alpha, proj_b, scal);
}

// Round 10
// 212.651 us; speedup vs baseline: 1.3035x; 1.0764x over previous
//
#include <hip/hip_runtime.h>

typedef unsigned short u16;
typedef unsigned int u32;
typedef __attribute__((ext_vector_type(8))) u16 u16x8;
typedef __attribute__((ext_vector_type(8))) __bf16 bf16x8;
typedef __attribute__((ext_vector_type(4))) float f32x4;

#define LOG2E_F 1.4426950408889634f

__device__ __forceinline__ u16 f2bf(float f) {
  return (u16)(__float_as_uint(f) >> 16);
}
__device__ __forceinline__ float clip87(float x) {
  return fminf(fmaxf(x, -8.0f), 7.0f);
}

// async global->LDS, 16B per lane; lptr must be wave-uniform (HW: lptr + lane*16)
typedef const __attribute__((address_space(1))) u32* gp32;
typedef __attribute__((address_space(3))) u32* lp32;
__device__ __forceinline__ void gl16(const void* g, void* l) {
  __builtin_amdgcn_global_load_lds((gp32)g, (lp32)l, 16, 0, 0);
}

// ---------------- scalar means + derived constants ----------------
// scal: [0]=a_in [1]=aq [2]=ak [3]=av [4]=am [5]=ap [6]=escale [7]=am*av
__global__ void k_scalars(const float* __restrict__ qkv_act_alpha,
                          const float* __restrict__ proj_act_alpha,
                          const float* __restrict__ q_alpha,
                          const float* __restrict__ k_alpha,
                          const float* __restrict__ v_alpha,
                          const float* __restrict__ attn_alpha,
                          float* __restrict__ scal) {
  int tid = threadIdx.x;
  int wave = tid >> 6, lane = tid & 63;
  if (wave < 6) {
    const float* src = nullptr; int n = 0;
    switch (wave) {
      case 0: src = qkv_act_alpha;  n = 768; break;
      case 1: src = q_alpha;        n = 12;  break;
      case 2: src = k_alpha;        n = 12;  break;
      case 3: src = v_alpha;        n = 12;  break;
      case 4: src = attn_alpha;     n = 12;  break;
      case 5: src = proj_act_alpha; n = 768; break;
    }
    double s = 0.0;
    for (int i = lane; i < n; i += 64) s += (double)src[i];
    s += __shfl_xor(s, 1);
    s += __shfl_xor(s, 2);
    s += __shfl_xor(s, 4);
    s += __shfl_xor(s, 8);
    s += __shfl_xor(s, 16);
    s += __shfl_xor(s, 32);
    if (lane == 0) scal[wave] = (float)(s / (double)n);
  }
  __syncthreads();
  if (tid == 0) {
    float aq = scal[1], ak = scal[2];
    float s_ = (0.125f * aq) * ak;   // head_scale * aq * ak
    scal[6] = LOG2E_F * s_;          // escale
    scal[7] = scal[4] * scal[3];     // am * av
  }
}

// ---------------- weight quantization ----------------
__global__ __launch_bounds__(256) void k_quant_weights(
    const float* __restrict__ qkv_w, const float* __restrict__ qkv_alpha,
    const float* __restrict__ qkv_b, const float* __restrict__ proj_w,
    const float* __restrict__ proj_alpha, const float* __restrict__ scal,
    u16* __restrict__ wq, u16* __restrict__ wp, float* __restrict__ biasi) {
  int idx = blockIdx.x * 256 + threadIdx.x;
  const int T1 = 2304 * 768, T2 = 768 * 768;
  if (idx < T1) {
    int o = idx / 768;
    wq[idx] = f2bf(rintf(clip87(qkv_w[idx] / qkv_alpha[o])));
  } else if (idx < T1 + T2) {
    int j = idx - T1;
    int o = j / 768;
    wp[j] = f2bf(rintf(clip87(proj_w[j] / proj_alpha[o])));
  } else if (idx < T1 + T2 + 2304) {
    int o = idx - T1 - T2;
    biasi[o] = truncf((qkv_b[o] / scal[0]) / qkv_alpha[o]);
  }
}

// ---------------- x0 activation quantization ----------------
__global__ __launch_bounds__(256) void k_quant_x0(const float* __restrict__ x0,
                                                  const float* __restrict__ scal,
                                                  u16* __restrict__ x0q) {
  int base = (blockIdx.x * 256 + threadIdx.x) * 8;
  float a = scal[0];
  f32x4 v0 = *(const f32x4*)&x0[base];
  f32x4 v1 = *(const f32x4*)&x0[base + 4];
  u16x8 o;
  #pragma unroll
  for (int j = 0; j < 4; j++) o[j] = f2bf(rintf(clip87(v0[j] / a)));
  #pragma unroll
  for (int j = 0; j < 4; j++) o[4 + j] = f2bf(rintf(clip87(v1[j] / a)));
  *(u16x8*)&x0q[base] = o;
}

// ================= shared GEMM core =================
// 128x128 tile, BK=64, double-buffered LDS, XOR-swizzled staging.
// Staging: wave w covers rows w*32..w*32+31, 4 issues of 8 rows each.
//   Lane l -> row-sub l>>3, stored 16B-block l&7; source block j=(l&7)^(l>>3)
//   (global source pre-swizzled so linear LDS dest holds swizzled layout).
// Read: row's block j stored at jj = j ^ (row&7); row&7 == lane&7 for all frags.
#define BUF_A(c) (smem_u16 + (c) * 8192)
#define BUF_B(c) (smem_u16 + 16384 + (c) * 8192)

__device__ __forceinline__ void stage_tile(const u16* gAl, const u16* gBl, int K,
                                           u16* bufA, u16* bufB, int w) {
  #pragma unroll
  for (int i = 0; i < 4; i++)
    gl16(gAl + (size_t)(i * 8) * K, bufA + (w * 32 + i * 8) * 64);
  #pragma unroll
  for (int i = 0; i < 4; i++)
    gl16(gBl + (size_t)(i * 8) * K, bufB + (w * 32 + i * 8) * 64);
}

__device__ __forceinline__ void gemm_steps(const u16* __restrict__ A,
                                           const u16* __restrict__ Bt, int K,
                                           int m0, int n0, u16* smem_u16,
                                           int lane, int wave, f32x4 acc[4][4]) {
  int rsub = lane >> 3;           // 0..7
  int jsrc = (lane & 7) ^ rsub;   // swizzled source block
  const u16* gAl = A + (size_t)(m0 + wave * 32 + rsub) * K + jsrc * 8;
  const u16* gBl = Bt + (size_t)(n0 + wave * 32 + rsub) * K + jsrc * 8;

  int arow = (wave >> 1) * 64 + (lane & 15);
  int brow = (wave & 1) * 64 + (lane & 15);
  int nsteps = K / 64;

  stage_tile(gAl, gBl, K, BUF_A(0), BUF_B(0), wave);
  __syncthreads();
  for (int t = 0; t < nsteps; t++) {
    int cur = t & 1;
    if (t + 1 < nsteps)
      stage_tile(gAl + (t + 1) * 64, gBl + (t + 1) * 64, K,
                 BUF_A(cur ^ 1), BUF_B(cur ^ 1), wave);
    const u16* bA = BUF_A(cur);
    const u16* bB = BUF_B(cur);
    #pragma unroll
    for (int kk = 0; kk < 2; kk++) {
      int jj = ((kk * 4 + (lane >> 4)) ^ (lane & 7)) * 8;
      bf16x8 af[4], bf[4];
      #pragma unroll
      for (int mi = 0; mi < 4; mi++) af[mi] = *(const bf16x8*)&bA[(arow + mi * 16) * 64 + jj];
      #pragma unroll
      for (int ni = 0; ni < 4; ni++) bf[ni] = *(const bf16x8*)&bB[(brow + ni * 16) * 64 + jj];
      #pragma unroll
      for (int mi = 0; mi < 4; mi++)
        #pragma unroll
        for (int ni = 0; ni < 4; ni++)
          acc[mi][ni] = __builtin_amdgcn_mfma_f32_16x16x32_bf16(af[mi], bf[ni], acc[mi][ni], 0, 0, 0);
    }
    __syncthreads();
  }
}

// ---------------- qkv GEMM with FUSED branch quantization ----------------
// grid (18, 32): bx -> branch = bx/6 (0=q,1=k,2=v), head pair hp = bx%6.
__global__ __launch_bounds__(256) void k_gemm_qkv(
    const u16* __restrict__ A, const u16* __restrict__ Bt,
    const float* __restrict__ biasi, const float* __restrict__ qkv_alpha,
    const float* __restrict__ nqw, const float* __restrict__ nqb,
    const float* __restrict__ nkw, const float* __restrict__ nkb,
    const float* __restrict__ scal,
    u16* __restrict__ q2, u16* __restrict__ k2, u16* __restrict__ v2t) {
  const int K = 768;
  __shared__ __align__(16) char smem[128 * 129 * 4];   // 66KB; >= 64KB staging
  u16* smem_u16 = (u16*)smem;
  float* xt = (float*)smem;
  int tid = threadIdx.x;
  int lane = tid & 63, wave = tid >> 6;
  int wr = wave >> 1, wc = wave & 1;
  int m0 = blockIdx.y * 128, n0 = blockIdx.x * 128;

  f32x4 acc[4][4];
  #pragma unroll
  for (int mi = 0; mi < 4; mi++)
    #pragma unroll
    for (int ni = 0; ni < 4; ni++) acc[mi][ni] = (f32x4){0.f, 0.f, 0.f, 0.f};

  gemm_steps(A, Bt, K, m0, n0, smem_u16, lane, wave, acc);
  // final barrier of gemm_steps: safe to repurpose smem as xt

  // ---- phase 1: raw qkv tile (acc + bias) -> LDS ----
  int lrow = (lane >> 4) * 4, lcol = lane & 15;
  #pragma unroll
  for (int mi = 0; mi < 4; mi++)
    #pragma unroll
    for (int ni = 0; ni < 4; ni++) {
      int c = wc * 64 + ni * 16 + lcol;
      float bs = biasi[n0 + c];
      #pragma unroll
      for (int rr = 0; rr < 4; rr++) {
        int r = wr * 64 + mi * 16 + lrow + rr;
        xt[r * 129 + c] = acc[mi][ni][rr] + bs;
      }
    }
  __syncthreads();

  // ---- phase 2: branch quantization ----
  int branch = blockIdx.x / 6, hp = blockIdx.x % 6;
  int b = m0 >> 10, nb = m0 & 1023;
  if (branch == 2) {
    // v: thread owns one column (head h, dim d); transpose-write v2t[bh][d][n]
    int c = tid & 127, hf = tid >> 7;
    int h = hp * 2 + (c >> 6), d = c & 63;
    float av = scal[3];
    float coefv = scal[0] * qkv_alpha[1536 + h * 64 + d];
    u16* dst = v2t + ((size_t)(b * 12 + h) * 64 + d) * 1024 + nb + hf * 64;
    #pragma unroll
    for (int g = 0; g < 8; g++) {
      u16x8 t8;
      #pragma unroll
      for (int j = 0; j < 8; j++) {
        float val = xt[(hf * 64 + g * 8 + j) * 129 + c];
        t8[j] = f2bf(rintf(clip87((val * coefv) / av)));
      }
      *(u16x8*)(dst + g * 8) = t8;
    }
  } else {
    // q/k: thread owns one row of one head; serial int mean/var recurrence
    int r = tid & 127, hs = tid >> 7;
    int h = hp * 2 + hs;
    const float* alph = qkv_alpha + branch * 768 + h * 64;
    const float* wv = branch == 0 ? nqw : nkw;
    const float* bv = branch == 0 ? nqb : nkb;
    float as = branch == 0 ? scal[1] : scal[2];
    float xq[64];
    #pragma unroll
    for (int d = 0; d < 64; d++) xq[d] = xt[r * 129 + hs * 64 + d] * alph[d];
    int m = 0, v = 0;
    #pragma unroll
    for (int i = 0; i < 64; i++) {
      int xi = (int)xq[i];
      int dd = xi - m;
      m += (dd * (1024 / (i + 1))) >> 10;   // floor div by 1024
      v += dd * (xi - m);
    }
    float muf = (float)m;
    float den = sqrtf((float)v * 0.015625f) + 1e-5f;
    u16* outp = (branch == 0 ? q2 : k2) + ((size_t)(b * 12 + h) * 1024 + nb + r) * 64;
    #pragma unroll
    for (int g = 0; g < 8; g++) {
      u16x8 t8;
      #pragma unroll
      for (int j = 0; j < 8; j++) {
        int d = g * 8 + j;
        float q1 = (xq[d] - muf) / den;
        float bw = bv[d] / wv[d];
        float t = (q1 + bw) * wv[d] / as;
        t8[j] = f2bf(rintf(clip87(t)));
      }
      *(u16x8*)(outp + g * 8) = t8;
    }
  }
}

// ---------------- proj GEMM: C = A * B^T, fused scale+bias epilogue ----------------
__global__ __launch_bounds__(256) void k_gemm_proj(
    const u16* __restrict__ A, const u16* __restrict__ Bt,
    float* __restrict__ Cout, const float* __restrict__ palpha,
    const float* __restrict__ pbias, const float* __restrict__ scal) {
  const int K = 768, N = 768;
  __shared__ __align__(16) char smem[65536];
  u16* smem_u16 = (u16*)smem;
  int tid = threadIdx.x;
  int lane = tid & 63, wave = tid >> 6;
  int wr = wave >> 1, wc = wave & 1;
  int m0 = blockIdx.y * 128, n0 = blockIdx.x * 128;

  f32x4 acc[4][4];
  #pragma unroll
  for (int mi = 0; mi < 4; mi++)
    #pragma unroll
    for (int ni = 0; ni < 4; ni++) acc[mi][ni] = (f32x4){0.f, 0.f, 0.f, 0.f};

  gemm_steps(A, Bt, K, m0, n0, smem_u16, lane, wave, acc);

  int lrow = (lane >> 4) * 4, lcol = lane & 15;
  float ap = scal[5];
  #pragma unroll
  for (int mi = 0; mi < 4; mi++)
    #pragma unroll
    for (int ni = 0; ni < 4; ni++) {
      int col = n0 + wc * 64 + ni * 16 + lcol;
      float pa = palpha[col], pb = pbias[col];
      #pragma unroll
      for (int rr = 0; rr < 4; rr++) {
        int row = m0 + wr * 64 + mi * 16 + lrow + rr;
        Cout[(size_t)row * N + col] = (acc[mi][ni][rr] * pa) * ap + pb;
      }
    }
}

// ---------------- fused attention ----------------
// grid (16, 48): qt = bx (64 q rows), bh = by. 4 waves; wave w owns q rows w*16..w*16+15.
__global__ __launch_bounds__(256) void k_attn(
    const u16* __restrict__ q2, const u16* __restrict__ k2,
    const u16* __restrict__ v2t, const float* __restrict__ scal,
    u16* __restrict__ x1q) {
  __shared__ __align__(16) u16 lK[64 * 72];
  __shared__ __align__(16) u16 lV[64 * 72];
  __shared__ __align__(16) u16 lP[64 * 72];
  __shared__ float rs_lds[64];
  int tid = threadIdx.x, lane = tid & 63, wave = tid >> 6;
  int qt = blockIdx.x, bh = blockIdx.y;
  const float escale = scal[6], am = scal[4], am_av = scal[7], apc = scal[5];

  size_t qrow = (size_t)bh * 1024 + qt * 64 + wave * 16 + (lane & 15);
  bf16x8 qf0 = *(const bf16x8*)(q2 + qrow * 64 + (lane >> 4) * 8);
  bf16x8 qf1 = *(const bf16x8*)(q2 + qrow * 64 + 32 + (lane >> 4) * 8);

  const u16* k2b = k2 + (size_t)bh * 1024 * 64;
  const u16* v2b = v2t + (size_t)bh * 64 * 1024;
  int sr = tid >> 2, sc = (tid & 3) * 16;

  // ---- pass 1: row sums of attn_exp (f32 per-kt partial, f64 across kt) ----
  double rsum[4] = {0.0, 0.0, 0.0, 0.0};
  for (int kt = 0; kt < 16; kt++) {
    const u16* src = k2b + (size_t)(kt * 64 + sr) * 64 + sc;
    *(u16x8*)&lK[sr * 72 + sc]     = *(const u16x8*)src;
    *(u16x8*)&lK[sr * 72 + sc + 8] = *(const u16x8*)(src + 8);
    __syncthreads();
    float part[4] = {0.f, 0.f, 0.f, 0.f};
    #pragma unroll
    for (int ct = 0; ct < 4; ct++) {
      bf16x8 kf0 = *(const bf16x8*)&lK[(ct * 16 + (lane & 15)) * 72 + (lane >> 4) * 8];
      bf16x8 kf1 = *(const bf16x8*)&lK[(ct * 16 + (lane & 15)) * 72 + 32 + (lane >> 4) * 8];
      f32x4 s = {0.f, 0.f, 0.f, 0.f};
      s = __builtin_amdgcn_mfma_f32_16x16x32_bf16(qf0, kf0, s, 0, 0, 0);
      s = __builtin_amdgcn_mfma_f32_16x16x32_bf16(qf1, kf1, s, 0, 0, 0);
      #pragma unroll
      for (int rr = 0; rr < 4; rr++) {
        float e = escale * s[rr];
        float f = floorf(e);
        float pe = ldexpf(1.0f + (e - f), (int)f);  // exact 2^f scaling
        part[rr] += pe;
      }
    }
    #pragma unroll
    for (int rr = 0; rr < 4; rr++) rsum[rr] += (double)part[rr];
    __syncthreads();
  }
  #pragma unroll
  for (int rr = 0; rr < 4; rr++) {
    double s = rsum[rr];
    s += __shfl_xor(s, 1);
    s += __shfl_xor(s, 2);
    s += __shfl_xor(s, 4);
    s += __shfl_xor(s, 8);
    if ((lane & 15) == 0) rs_lds[wave * 16 + (lane >> 4) * 4 + rr] = (float)s;
  }
  __syncthreads();
  float fac[4];
  #pragma unroll
  for (int rr = 0; rr < 4; rr++)
    fac[rr] = 1.0f / (rs_lds[wave * 16 + (lane >> 4) * 4 + rr] * am);

  // ---- pass 2: recompute S (bitwise identical), quantize attn, PV GEMM ----
  f32x4 accv[4];
  #pragma unroll
  for (int ct = 0; ct < 4; ct++) accv[ct] = (f32x4){0.f, 0.f, 0.f, 0.f};

  for (int kt = 0; kt < 16; kt++) {
    const u16* srcK = k2b + (size_t)(kt * 64 + sr) * 64 + sc;
    *(u16x8*)&lK[sr * 72 + sc]     = *(const u16x8*)srcK;
    *(u16x8*)&lK[sr * 72 + sc + 8] = *(const u16x8*)(srcK + 8);
    const u16* srcV = v2b + (size_t)sr * 1024 + kt * 64 + sc;
    *(u16x8*)&lV[sr * 72 + sc]     = *(const u16x8*)srcV;
    *(u16x8*)&lV[sr * 72 + sc + 8] = *(const u16x8*)(srcV + 8);
    __syncthreads();
    #pragma unroll
    for (int ct = 0; ct < 4; ct++) {
      bf16x8 kf0 = *(const bf16x8*)&lK[(ct * 16 + (lane & 15)) * 72 + (lane >> 4) * 8];
      bf16x8 kf1 = *(const bf16x8*)&lK[(ct * 16 + (lane & 15)) * 72 + 32 + (lane >> 4) * 8];
      f32x4 s = {0.f, 0.f, 0.f, 0.f};
      s = __builtin_amdgcn_mfma_f32_16x16x32_bf16(qf0, kf0, s, 0, 0, 0);
      s = __builtin_amdgcn_mfma_f32_16x16x32_bf16(qf1, kf1, s, 0, 0, 0);
      #pragma unroll
      for (int rr = 0; rr < 4; rr++) {
        float e = escale * s[rr];
        float f = floorf(e);
        float pe = ldexpf(1.0f + (e - f), (int)f);
        float a2 = rintf(fminf(pe * fac[rr], 7.0f));
        lP[(wave * 16 + (lane >> 4) * 4 + rr) * 72 + ct * 16 + (lane & 15)] = f2bf(a2);
      }
    }
    __syncthreads();
    bf16x8 pf0 = *(const bf16x8*)&lP[(wave * 16 + (lane & 15)) * 72 + (lane >> 4) * 8];
    bf16x8 pf1 = *(const bf16x8*)&lP[(wave * 16 + (lane & 15)) * 72 + 32 + (lane >> 4) * 8];
    #pragma unroll
    for (int ct = 0; ct < 4; ct++) {
      bf16x8 vf0 = *(const bf16x8*)&lV[(ct * 16 + (lane & 15)) * 72 + (lane >> 4) * 8];
      bf16x8 vf1 = *(const bf16x8*)&lV[(ct * 16 + (lane & 15)) * 72 + 32 + (lane >> 4) * 8];
      accv[ct] = __builtin_amdgcn_mfma_f32_16x16x32_bf16(pf0, vf0, accv[ct], 0, 0, 0);
      accv[ct] = __builtin_amdgcn_mfma_f32_16x16x32_bf16(pf1, vf1, accv[ct], 0, 0, 0);
    }
    __syncthreads();
  }

  int b = bh / 12, h = bh % 12;
  #pragma unroll
  for (int ct = 0; ct < 4; ct++)
    #pragma unroll
    for (int rr = 0; rr < 4; rr++) {
      int qr = qt * 64 + wave * 16 + (lane >> 4) * 4 + rr;
      int col = h * 64 + ct * 16 + (lane & 15);
      float t = (accv[ct][rr] * am_av) / apc;
      x1q[((size_t)b * 1024 + qr) * 768 + col] = f2bf(rintf(clip87(t)));
    }
}

extern "C" void kernel_launch(void* const* d_in, const int* in_sizes, int n_in,
                              void* d_out, int out_size, void* d_ws, size_t ws_size,
                              hipStream_t stream) {
  const float* x0             = (const float*)d_in[0];
  const float* qkv_w          = (const float*)d_in[1];
  const float* qkv_b          = (const float*)d_in[2];
  const float* qkv_alpha      = (const float*)d_in[3];
  const float* qkv_act_alpha  = (const float*)d_in[4];
  const float* proj_w         = (const float*)d_in[5];
  const float* proj_b         = (const float*)d_in[6];
  const float* proj_alpha     = (const float*)d_in[7];
  const float* proj_act_alpha = (const float*)d_in[8];
  const float* nqw            = (const float*)d_in[9];
  const float* nqb            = (const float*)d_in[10];
  const float* nkw            = (const float*)d_in[11];
  const float* nkb            = (const float*)d_in[12];
  const float* q_alpha        = (const float*)d_in[13];
  const float* k_alpha        = (const float*)d_in[14];
  const float* v_alpha        = (const float*)d_in[15];
  const float* attn_alpha     = (const float*)d_in[16];
  float* out = (float*)d_out;

  char* ws = (char*)d_ws;
  size_t off = 0;
  auto alloc = [&](size_t bytes) -> void* {
    off = (off + 255) & ~(size_t)255;
    void* p = ws + off;
    off += bytes;
    return p;
  };
  float* scal = (float*)alloc(64);
  u16* wq     = (u16*)alloc((size_t)2304 * 768 * 2);
  u16* wp     = (u16*)alloc((size_t)768 * 768 * 2);
  float* biasi= (float*)alloc((size_t)2304 * 4);
  u16* x0q    = (u16*)alloc((size_t)4096 * 768 * 2);
  u16* q2     = (u16*)alloc((size_t)48 * 1024 * 64 * 2);
  u16* k2     = (u16*)alloc((size_t)48 * 1024 * 64 * 2);
  u16* v2t    = (u16*)alloc((size_t)48 * 1024 * 64 * 2);
  u16* x1q    = (u16*)alloc((size_t)4096 * 768 * 2);

  k_scalars<<<1, 384, 0, stream>>>(qkv_act_alpha, proj_act_alpha, q_alpha, k_alpha,
                                   v_alpha, attn_alpha, scal);

  int totW = 2304 * 768 + 768 * 768 + 2304;
  k_quant_weights<<<(totW + 255) / 256, 256, 0, stream>>>(qkv_w, qkv_alpha, qkv_b,
                                                          proj_w, proj_alpha, scal,
                                                          wq, wp, biasi);

  k_quant_x0<<<(4096 * 768) / (256 * 8), 256, 0, stream>>>(x0, scal, x0q);

  k_gemm_qkv<<<dim3(18, 32), 256, 0, stream>>>(x0q, wq, biasi, qkv_alpha,
                                               nqw, nqb, nkw, nkb, scal,
                                               q2, k2, v2t);

  k_attn<<<dim3(16, 48), 256, 0, stream>>>(q2, k2, v2t, scal, x1q);

  k_gemm_proj<<<dim3(6, 32), 256, 0, stream>>>(x1q, wp, out, proj_alpha, proj_b, scal);
}